// Round 18
// baseline (187.233 us; speedup 1.0000x reference)
//
#include <hip/hip_runtime.h>
#include <hip/hip_bf16.h>
#include <stdint.h>

// Problem constants
#define BB 2
#define LL 512
#define DIN 256
#define HH 8
#define DKK 32
#define NN 128
#define DM 256            // D_OUT / model dim
#define SCALING 0.17677669529663687f

typedef unsigned short u16;
typedef float f32x4 __attribute__((ext_vector_type(4)));
typedef short s16x8 __attribute__((ext_vector_type(8)));

#define MFMA16(a, b, c) __builtin_amdgcn_mfma_f32_16x16x32_bf16((a), (b), (c), 0, 0, 0)

typedef __attribute__((address_space(3))) char lds_char;
typedef const __attribute__((address_space(1))) char glb_char;

__device__ __forceinline__ void gload16(const void* g, void* l) {
    __builtin_amdgcn_global_load_lds((glb_char*)g, (lds_char*)l, 16, 0, 0);
}

__device__ __forceinline__ u16 f2bf(float f) {
    union { float f; uint32_t i; } v; v.f = f;
    uint32_t x = v.i;
    return (u16)((x + 0x7fffu + ((x >> 16) & 1u)) >> 16);   // RNE
}

// pack 2 floats -> 2 bf16 (round-half-up) in one u32 via v_perm
__device__ __forceinline__ uint32_t pack2bf(float f0, float f1) {
    union { float f; uint32_t i; } a, b;
    a.f = f0; b.f = f1;
    return __builtin_amdgcn_perm(b.i + 0x8000u, a.i + 0x8000u, 0x07060302u);
}

// swizzled LDS frag read, 128B rows (BK=64 bf16): 16B at (row, byte-col cb)
__device__ __forceinline__ s16x8 ldsfrag(const u16* base, int row, int cb) {
    const char* p = (const char*)base + row * 128 + (cb ^ ((row & 7) << 4));
    return *(const s16x8*)(const void*)p;
}

// ---------------------------------------------------------------------------
// Kernel 1: transpose Wq,Wk,Wv,Wo to bf16, K-major (WT[c][k] = W[k][c])
// ---------------------------------------------------------------------------
__global__ __launch_bounds__(256) void prep_weights(
        const float* __restrict__ Wq, const float* __restrict__ Wk,
        const float* __restrict__ Wv, const float* __restrict__ Wo,
        u16* __restrict__ wqt, u16* __restrict__ wkt,
        u16* __restrict__ wvt, u16* __restrict__ wot) {
    int idx = blockIdx.x * 256 + threadIdx.x;      // 0 .. 262143
    int which = idx >> 16;
    const float* src = (which == 0) ? Wq : (which == 1) ? Wk : (which == 2) ? Wv : Wo;
    u16* dst = (which == 0) ? wqt : (which == 1) ? wkt : (which == 2) ? wvt : wot;
    int i = idx & 65535;
    int c = i & 255;
    int k = i >> 8;
    dst[(size_t)c * 256 + k] = f2bf(src[(size_t)k * 256 + c]);
}

// ---------------------------------------------------------------------------
// Kernel 2 (MFMA): q = (query@Wq+bq)*scale, k = key@Wk+bk -> bf16 [b][h][l][32]
// ---------------------------------------------------------------------------
__global__ __launch_bounds__(256) void qk_proj(
        const float* __restrict__ q_in, const float* __restrict__ k_in,
        const u16* __restrict__ wqt, const float* __restrict__ bq,
        const u16* __restrict__ wkt, const float* __restrict__ bk,
        u16* __restrict__ q_ws, u16* __restrict__ k_ws) {
    int bid = blockIdx.x;          // 0..31
    int isK = bid & 1;
    int r0 = (bid >> 1) * 64;
    const float* src = isK ? k_in : q_in;
    const u16* wt    = isK ? wkt : wqt;
    const float* bias = isK ? bk : bq;
    u16* dst = isK ? k_ws : q_ws;
    float scale = isK ? 1.0f : SCALING;

    int t = threadIdx.x, w = t >> 6, l = t & 63, lr = l & 15, lg = l >> 4;

    f32x4 zero = {0.f, 0.f, 0.f, 0.f};
    f32x4 acc[4][4];
#pragma unroll
    for (int m = 0; m < 4; m++)
#pragma unroll
        for (int cf = 0; cf < 4; cf++) acc[m][cf] = zero;

#pragma unroll
    for (int ks = 0; ks < 8; ks++) {
        s16x8 afr[4];
#pragma unroll
        for (int m = 0; m < 4; m++) {
            const float* p = src + (size_t)(r0 + m * 16 + lr) * DIN + ks * 32 + lg * 8;
            float4 v0 = *(const float4*)p;
            float4 v1 = *(const float4*)(p + 4);
            union { u16 u[8]; s16x8 v; } tmp;
            tmp.u[0] = f2bf(v0.x); tmp.u[1] = f2bf(v0.y);
            tmp.u[2] = f2bf(v0.z); tmp.u[3] = f2bf(v0.w);
            tmp.u[4] = f2bf(v1.x); tmp.u[5] = f2bf(v1.y);
            tmp.u[6] = f2bf(v1.z); tmp.u[7] = f2bf(v1.w);
            afr[m] = tmp.v;
        }
        s16x8 bfrg[4];
#pragma unroll
        for (int cf = 0; cf < 4; cf++)
            bfrg[cf] = *(const s16x8*)(const void*)(wt + (size_t)(w * 64 + cf * 16 + lr) * 256 + ks * 32 + lg * 8);
#pragma unroll
        for (int m = 0; m < 4; m++)
#pragma unroll
            for (int cf = 0; cf < 4; cf++) acc[m][cf] = MFMA16(afr[m], bfrg[cf], acc[m][cf]);
    }

#pragma unroll
    for (int m = 0; m < 4; m++)
#pragma unroll
        for (int cf = 0; cf < 4; cf++) {
            int c = w * 64 + cf * 16 + lr;
            int h = c >> 5, dd = c & 31;
            float bv_ = bias[c];
#pragma unroll
            for (int r = 0; r < 4; r++) {
                int row = r0 + m * 16 + 4 * lg + r;
                int b = row >> 9, li = row & 511;
                dst[(((size_t)(b * HH + h)) * LL + li) * DKK + dd] = f2bf((acc[m][cf][r] + bv_) * scale);
            }
        }
}

// ---------------------------------------------------------------------------
// Kernel 3: scores = q@k^T, mask, softmax -> attn bf16 [b][h][i][j]
// ---------------------------------------------------------------------------
__global__ __launch_bounds__(256) void scores_softmax(
        const u16* __restrict__ q_ws, const u16* __restrict__ k_ws,
        const float* __restrict__ mask, u16* __restrict__ attn) {
    int bid = blockIdx.x;
    int it = bid & 15;
    int bh = bid >> 4;
    int b = bh >> 3;
    int i0 = it * 32;

    __shared__ u16 kl[LL][40];
    __shared__ u16 ql[32][40];
    __shared__ float redmx[2][32];
    __shared__ float redsm[2][32];

    int t = threadIdx.x;
    const u16* kbase = k_ws + (size_t)bh * LL * DKK;
#pragma unroll
    for (int x = 0; x < 8; x++) {
        int idx = x * 256 + t;
        int row = idx >> 2, ch = idx & 3;
        *(s16x8*)(void*)(&kl[row][ch * 8]) = *(const s16x8*)(const void*)(kbase + (size_t)row * DKK + ch * 8);
    }
    if (t < 128) {
        const u16* qbase = q_ws + (size_t)bh * LL * DKK + (size_t)i0 * DKK;
        int row = t >> 2, ch = t & 3;
        *(s16x8*)(void*)(&ql[row][ch * 8]) = *(const s16x8*)(const void*)(qbase + (size_t)row * DKK + ch * 8);
    }
    __syncthreads();

    int w = t >> 6, l = t & 63, lr = l & 15, lg = l >> 4;
    int ih = (w & 1) * 16;
    int jh = (w >> 1) * 256;
    int jhalf = w >> 1;

    s16x8 af = *(const s16x8*)(const void*)(&ql[ih + lr][lg * 8]);
    f32x4 zero = {0.f, 0.f, 0.f, 0.f};
    f32x4 acc[16];
#pragma unroll
    for (int cf = 0; cf < 16; cf++) {
        s16x8 bf = *(const s16x8*)(const void*)(&kl[jh + cf * 16 + lr][lg * 8]);
        acc[cf] = MFMA16(af, bf, zero);
    }

    const float* mrow = mask + (size_t)b * LL * LL;
    float attv[16][4];
    float mx[4], sm[4];
#pragma unroll
    for (int r = 0; r < 4; r++) mx[r] = -3.0e38f;
#pragma unroll
    for (int cf = 0; cf < 16; cf++) {
#pragma unroll
        for (int r = 0; r < 4; r++) {
            int irow = i0 + ih + 4 * lg + r;
            int jcol = jh + cf * 16 + lr;
            float mv = mrow[(size_t)irow * LL + jcol];
            float s = (mv < 0.5f) ? -1.0e30f : acc[cf][r];
            attv[cf][r] = s;
            mx[r] = fmaxf(mx[r], s);
        }
    }
#pragma unroll
    for (int d = 1; d < 16; d <<= 1)
#pragma unroll
        for (int r = 0; r < 4; r++) mx[r] = fmaxf(mx[r], __shfl_xor(mx[r], d));
#pragma unroll
    for (int r = 0; r < 4; r++) sm[r] = 0.f;
#pragma unroll
    for (int cf = 0; cf < 16; cf++)
#pragma unroll
        for (int r = 0; r < 4; r++) {
            float p = __expf(attv[cf][r] - mx[r]);
            attv[cf][r] = p;
            sm[r] += p;
        }
#pragma unroll
    for (int d = 1; d < 16; d <<= 1)
#pragma unroll
        for (int r = 0; r < 4; r++) sm[r] += __shfl_xor(sm[r], d);

    if (lr == 0) {
#pragma unroll
        for (int r = 0; r < 4; r++) {
            redmx[jhalf][ih + 4 * lg + r] = mx[r];
            redsm[jhalf][ih + 4 * lg + r] = sm[r];
        }
    }
    __syncthreads();
    float inv[4];
#pragma unroll
    for (int r = 0; r < 4; r++) {
        int row = ih + 4 * lg + r;
        float m0 = redmx[0][row], m1 = redmx[1][row];
        float s0 = redsm[0][row], s1 = redsm[1][row];
        float gm = fmaxf(m0, m1);
        float gs = s0 * __expf(m0 - gm) + s1 * __expf(m1 - gm);
        inv[r] = __expf(mx[r] - gm) / gs;
    }

    u16* abase = attn + (size_t)bh * LL * LL;
#pragma unroll
    for (int cf = 0; cf < 16; cf++)
#pragma unroll
        for (int r = 0; r < 4; r++) {
            int irow = i0 + ih + 4 * lg + r;
            int jcol = jh + cf * 16 + lr;
            abase[(size_t)irow * LL + jcol] = f2bf(attv[cf][r] * inv[r]);
        }
}

// ---------------------------------------------------------------------------
// Kernel 4 (vproj_gemm, round-17 exact): C-write -> ut2 layout
// ut2[b][h][n][cl][j] = sum_k wvt[h*32+cl][k]*value[b,n,j][k] + bv
// ---------------------------------------------------------------------------
__global__ __launch_bounds__(256, 2) void vproj_gemm(
        const float* __restrict__ value, const float* __restrict__ bv,
        const u16* __restrict__ wvt, u16* __restrict__ ut) {
    __shared__ __align__(16) u16 sm[2 * 16384];    // per buf: A 16KB + B 16KB

    int t = threadIdx.x;
    int nb = gridDim.x;
    int cpx = nb >> 3;
    int swz = (blockIdx.x & 7) * cpx + (blockIdx.x >> 3);
    int ct = swz & 1;
    int jt = (swz >> 1) & 3;
    int bn = swz >> 3;
    int b = bn >> 7, n_ = bn & 127;
    int c0 = ct * 128, j0 = jt * 128;

    int w = t >> 6, l = t & 63, lr = l & 15, lg = l >> 4;
    int wr = w >> 1, wc = w & 1;

    const float* vbase = value + ((size_t)bn * LL + j0) * DM;

    int srow = t >> 3;         // 0..31 (x adds 32 per step)
    int sgc = t & 7;           // 16B-granule column
    f32x4 zero = {0.f, 0.f, 0.f, 0.f};
    f32x4 acc[4][4];
#pragma unroll
    for (int m = 0; m < 4; m++)
#pragma unroll
        for (int nf = 0; nf < 4; nf++) acc[m][nf] = zero;

    auto stageA = [&](int buf, int kk) {
#pragma unroll
        for (int x = 0; x < 4; x++) {
            int row = x * 32 + srow;
            int gs = sgc ^ (row & 7);
            gload16(wvt + (size_t)(c0 + row) * 256 + kk * 64 + gs * 8,
                    (char*)&sm[buf * 16384] + (x * 256 + t) * 16);
        }
    };
    float4 breg[2][4][2];      // 2 prefetch sets
    auto loadB = [&](int set, int kk) {
#pragma unroll
        for (int x = 0; x < 4; x++) {
            int row = x * 32 + srow;
            const float* p = vbase + (size_t)row * DM + kk * 64 + sgc * 8;
            breg[set][x][0] = *(const float4*)p;
            breg[set][x][1] = *(const float4*)(p + 4);
        }
    };
    auto writeB = [&](int buf, int set) {
#pragma unroll
        for (int x = 0; x < 4; x++) {
            int row = x * 32 + srow;
            uint32_t p0 = pack2bf(breg[set][x][0].x, breg[set][x][0].y);
            uint32_t p1 = pack2bf(breg[set][x][0].z, breg[set][x][0].w);
            uint32_t p2 = pack2bf(breg[set][x][1].x, breg[set][x][1].y);
            uint32_t p3 = pack2bf(breg[set][x][1].z, breg[set][x][1].w);
            uint32_t* dst = (uint32_t*)((char*)&sm[buf * 16384 + 8192]
                            + row * 128 + ((sgc * 16) ^ ((row & 7) << 4)));
            dst[0] = p0; dst[1] = p1; dst[2] = p2; dst[3] = p3;
        }
    };

    stageA(0, 0);
    loadB(0, 0);
    loadB(1, 1);               // prefetch depth 2
    writeB(0, 0);              // reg-wait retires stageA(0)+loadB(0)
    asm volatile("s_waitcnt vmcnt(8) lgkmcnt(0)" ::: "memory");
    __builtin_amdgcn_s_barrier();
    int cur = 0;
#pragma unroll
    for (int kk = 0; kk < 4; kk++) {
        if (kk < 3) stageA(cur ^ 1, kk + 1);
        if (kk < 2) loadB(kk & 1, kk + 2);     // issue 2 steps ahead
        const u16* Ab = &sm[cur * 16384];
        const u16* Bb = &sm[cur * 16384 + 8192];
        s16x8 af[4][2], bf[4][2];
#pragma unroll
        for (int m = 0; m < 4; m++)
#pragma unroll
            for (int ks = 0; ks < 2; ks++)
                af[m][ks] = ldsfrag(Ab, wr * 64 + m * 16 + lr, ks * 64 + lg * 16);
#pragma unroll
        for (int nf = 0; nf < 4; nf++)
#pragma unroll
            for (int ks = 0; ks < 2; ks++)
                bf[nf][ks] = ldsfrag(Bb, wc * 64 + nf * 16 + lr, ks * 64 + lg * 16);
#pragma unroll
        for (int ks = 0; ks < 2; ks++)
#pragma unroll
            for (int m = 0; m < 4; m++)
#pragma unroll
                for (int nf = 0; nf < 4; nf++)
                    acc[m][nf] = MFMA16(af[m][ks], bf[nf][ks], acc[m][nf]);
        if (kk < 3) writeB(cur ^ 1, (kk + 1) & 1);
        // counted-vmcnt barrier: keep loadB prefetch in flight
        if (kk < 2) {
            asm volatile("s_waitcnt vmcnt(8) lgkmcnt(0)" ::: "memory");
            __builtin_amdgcn_s_barrier();
        } else if (kk == 2) {
            asm volatile("s_waitcnt vmcnt(0) lgkmcnt(0)" ::: "memory");
            __builtin_amdgcn_s_barrier();
        }
        cur ^= 1;
    }

    // scalar C-write, ut2 layout: (((b*HH + h)*NN + n)*DKK + cl)*LL + j
#pragma unroll
    for (int m = 0; m < 4; m++) {
#pragma unroll
        for (int rr = 0; rr < 4; rr++) {
            int c = c0 + wr * 64 + m * 16 + 4 * lg + rr;
            int h = c >> 5, cl = c & 31;
            float bvv = bv[c];
            u16* dst = ut + ((((size_t)(b * HH + h)) * NN + n_) * DKK + cl) * LL + j0;
#pragma unroll
            for (int nf = 0; nf < 4; nf++) {
                int j_l = wc * 64 + nf * 16 + lr;
                dst[j_l] = f2bf(acc[m][nf][rr] + bvv);
            }
        }
    }
}

// ---------------------------------------------------------------------------
// Kernel 5 (pv8): 8-phase-style counted-vmcnt schedule, 128x128 tile, BK=64.
// Each K-tile split into 2 column-halves (k 0-31 / 32-63); per half-region
// [128 rows][64B], granule XOR gs = gc ^ ((row>>1)&3)  (2-way banks = free).
// Per K-tile: 2 phases of {ds_read 8 frags; issue half-stage of future
// K-tile; barrier; lgkmcnt(0)+sched_barrier; setprio(1); 16 MFMA; setprio(0);
// barrier}; vmcnt(4) only at K-tile boundary (12 loads in flight steady).
// ---------------------------------------------------------------------------
__global__ __launch_bounds__(256, 2) void pv_gemm(
        const u16* __restrict__ attn, const u16* __restrict__ ut,
        u16* __restrict__ Tm, int n0, int nTiles, int Nc) {
    __shared__ __align__(16) u16 sm[32768];        // 64 KB:
    // A half-regions: (buf*2+hf)*4096      (4 x 8KB)
    // B half-regions: 16384 + (buf*2+hf)*4096

    int t = threadIdx.x;
    int nb = gridDim.x;
    int cpx = nb >> 3;
    int swz = (blockIdx.x & 7) * cpx + (blockIdx.x >> 3);
    int nct = swz % nTiles;
    int tmp2 = swz / nTiles;
    int it = tmp2 & 3;
    int bh = tmp2 >> 2;
    int b = bh >> 3, hh = bh & 7;
    int i0 = it * 128;

    int w = t >> 6, l = t & 63, lr = l & 15, lg = l >> 4;
    int wr = w >> 1, wc = w & 1;

    const u16* arow0 = attn + (size_t)bh * LL * LL + (size_t)i0 * LL;
    const u16* uB = ut + (((size_t)(b * HH + hh)) * NN + n0) * DKK * LL;

    f32x4 zero = {0.f, 0.f, 0.f, 0.f};
    f32x4 acc[4][4];
#pragma unroll
    for (int m = 0; m < 4; m++)
#pragma unroll
        for (int nf = 0; nf < 4; nf++) acc[m][nf] = zero;

    // half-stage: A half + B half of K-tile kt into buf (4 loads/thread)
    auto hstage = [&](int buf, int kt, int hf) {
#pragma unroll
        for (int x = 0; x < 2; x++) {              // A: 128 rows x 64B
            int G = x * 256 + t;
            int row = G >> 2, gc = G & 3;
            int gs = gc ^ ((row >> 1) & 3);
            gload16(arow0 + (size_t)row * LL + kt * 64 + hf * 32 + gs * 8,
                    (char*)&sm[(buf * 2 + hf) * 4096] + G * 16);
        }
#pragma unroll
        for (int x = 0; x < 2; x++) {              // B: 128 rows x 64B
            int G = x * 256 + t;
            int row = G >> 2, gc = G & 3;
            int gs = gc ^ ((row >> 1) & 3);
            gload16(uB + (size_t)(nct * 128 + row) * LL + kt * 64 + hf * 32 + gs * 8,
                    (char*)&sm[16384 + (buf * 2 + hf) * 4096] + G * 16);
        }
    };
    auto rdA = [&](int buf, int hf, int m) -> s16x8 {
        int row = wr * 64 + m * 16 + lr;
        const char* p = (const char*)&sm[(buf * 2 + hf) * 4096]
                      + row * 64 + ((lg ^ ((row >> 1) & 3)) << 4);
        return *(const s16x8*)(const void*)p;
    };
    auto rdB = [&](int buf, int hf, int nf) -> s16x8 {
        int row = wc * 64 + nf * 16 + lr;
        const char* p = (const char*)&sm[16384 + (buf * 2 + hf) * 4096]
                      + row * 64 + ((lg ^ ((row >> 1) & 3)) << 4);
        return *(const s16x8*)(const void*)p;
    };

    // prologue: k0 both halves + k1 h0  (12 loads/thread in flight)
    hstage(0, 0, 0);
    hstage(0, 0, 1);
    hstage(1, 1, 0);
    asm volatile("s_waitcnt vmcnt(4)" ::: "memory");   // k0 fully resident
    __builtin_amdgcn_s_barrier();

    for (int kt = 0; kt < 8; kt++) {
        int cur = kt & 1;
        // ---- phase 0 (ks = 0) ----
        s16x8 a0[4], b0[4];
#pragma unroll
        for (int m = 0; m < 4; m++) a0[m] = rdA(cur, 0, m);
#pragma unroll
        for (int nf = 0; nf < 4; nf++) b0[nf] = rdB(cur, 0, nf);
        if (kt < 7) hstage(cur ^ 1, kt + 1, 1);
        __builtin_amdgcn_s_barrier();
        asm volatile("s_waitcnt lgkmcnt(0)" ::: "memory");
        __builtin_amdgcn_sched_barrier(0);
        __builtin_amdgcn_s_setprio(1);
#pragma unroll
        for (int m = 0; m < 4; m++)
#pragma unroll
            for (int nf = 0; nf < 4; nf++)
                acc[m][nf] = MFMA16(a0[m], b0[nf], acc[m][nf]);
        __builtin_amdgcn_s_setprio(0);
        __builtin_amdgcn_s_barrier();
        // ---- phase 1 (ks = 1) ----
        s16x8 a1[4], b1[4];
#pragma unroll
        for (int m = 0; m < 4; m++) a1[m] = rdA(cur, 1, m);
#pragma unroll
        for (int nf = 0; nf < 4; nf++) b1[nf] = rdB(cur, 1, nf);
        if (kt < 6) hstage(cur, kt + 2, 0);        // overwrites (cur,h0): all
                                                   // waves done reading it
        __builtin_amdgcn_s_barrier();
        asm volatile("s_waitcnt lgkmcnt(0)" ::: "memory");
        __builtin_amdgcn_sched_barrier(0);
        __builtin_amdgcn_s_setprio(1);
#pragma unroll
        for (int m = 0; m < 4; m++)
#pragma unroll
            for (int nf = 0; nf < 4; nf++)
                acc[m][nf] = MFMA16(a1[m], b1[nf], acc[m][nf]);
        __builtin_amdgcn_s_setprio(0);
        // ---- K-tile boundary: ensure K-tile kt+1 resident, keep rest flying
        if (kt < 6)      asm volatile("s_waitcnt vmcnt(4)" ::: "memory");
        else if (kt == 6) asm volatile("s_waitcnt vmcnt(0)" ::: "memory");
        __builtin_amdgcn_s_barrier();
    }

    // scalar C-write, Tm layout unchanged
#pragma unroll
    for (int m = 0; m < 4; m++) {
        int i = i0 + wr * 64 + m * 16 + 4 * lg;
#pragma unroll
        for (int nf = 0; nf < 4; nf++) {
            int nc = nct * 128 + wc * 64 + nf * 16 + lr;
            int nl = nc >> 5, cl = nc & 31;
            u16* dst = Tm + (((size_t)(b * Nc + nl)) * LL + i) * DM + hh * DKK + cl;
#pragma unroll
            for (int rr = 0; rr < 4; rr++)
                dst[(size_t)rr * DM] = f2bf(acc[m][nf][rr]);
        }
    }
}

// ---------------------------------------------------------------------------
// Kernel 6 (wo, round-17 exact): out[r][o] = sum_cc T[r][cc]*wot[o][cc]+bo[o]
// ---------------------------------------------------------------------------
__global__ __launch_bounds__(256, 2) void wo_gemm(
        const u16* __restrict__ Tm, const u16* __restrict__ wot,
        const float* __restrict__ bo, float* __restrict__ out,
        int n0, int Nc, int nshift) {
    __shared__ __align__(16) u16 sm[2 * 16384];

    int t = threadIdx.x;
    int nb = gridDim.x;
    int cpx = nb >> 3;
    int swz = (blockIdx.x & 7) * cpx + (blockIdx.x >> 3);
    int oc = swz & 1;
    int mt = swz >> 1;
    int r0 = mt * 128;

    int w = t >> 6, l = t & 63, lr = l & 15, lg = l >> 4;
    int wr = w >> 1, wc = w & 1;

    f32x4 zero = {0.f, 0.f, 0.f, 0.f};
    f32x4 acc[4][4];
#pragma unroll
    for (int m = 0; m < 4; m++)
#pragma unroll
        for (int nf = 0; nf < 4; nf++) acc[m][nf] = zero;

    auto stage = [&](int buf, int kk) {
#pragma unroll
        for (int x = 0; x < 4; x++) {              // A: T rows
            int G = x * 256 + t;
            int row = G >> 3, gc = G & 7;
            int gs = gc ^ (row & 7);
            gload16(Tm + (size_t)(r0 + row) * DM + kk * 64 + gs * 8,
                    (char*)&sm[buf * 16384] + G * 16);
        }
#pragma unroll
        for (int x = 0; x < 4; x++) {              // B: wot rows
            int G = x * 256 + t;
            int row = G >> 3, gc = G & 7;
            int gs = gc ^ (row & 7);
            gload16(wot + (size_t)(oc * 128 + row) * DM + kk * 64 + gs * 8,
                    (char*)&sm[buf * 16384 + 8192] + G * 16);
        }
    };

    stage(0, 0);
    __syncthreads();
    int cur = 0;
    for (int kk = 0; kk < 4; kk++) {
        if (kk < 3) stage(cur ^ 1, kk + 1);
        const u16* Ab = &sm[cur * 16384];
        const u16* Bb = &sm[cur * 16384 + 8192];
        s16x8 af[4][2], bf[4][2];
#pragma unroll
        for (int m = 0; m < 4; m++)
#pragma unroll
            for (int ks = 0; ks < 2; ks++)
                af[m][ks] = ldsfrag(Ab, wr * 64 + m * 16 + lr, ks * 64 + lg * 16);
#pragma unroll
        for (int nf = 0; nf < 4; nf++)
#pragma unroll
            for (int ks = 0; ks < 2; ks++)
                bf[nf][ks] = ldsfrag(Bb, wc * 64 + nf * 16 + lr, ks * 64 + lg * 16);
#pragma unroll
        for (int ks = 0; ks < 2; ks++)
#pragma unroll
            for (int m = 0; m < 4; m++)
#pragma unroll
                for (int nf = 0; nf < 4; nf++)
                    acc[m][nf] = MFMA16(af[m][ks], bf[nf][ks], acc[m][nf]);
        __syncthreads();
        cur ^= 1;
    }

#pragma unroll
    for (int nf = 0; nf < 4; nf++) {
        int ocol = oc * 128 + wc * 64 + nf * 16 + lr;
        float bov = bo[ocol];
#pragma unroll
        for (int m = 0; m < 4; m++) {
            int rbase = r0 + wr * 64 + m * 16 + 4 * lg;
#pragma unroll
            for (int rr = 0; rr < 4; rr++) {
                int r = rbase + rr;
                int bnl = r >> 9, i = r & 511;
                int b = bnl >> nshift, nl = bnl & (Nc - 1);
                out[(((size_t)(b * NN + n0 + nl)) * LL + i) * DM + ocol] = acc[m][nf][rr] + bov;
            }
        }
    }
}

// ---------------------------------------------------------------------------
extern "C" void kernel_launch(void* const* d_in, const int* in_sizes, int n_in,
                              void* d_out, int out_size, void* d_ws, size_t ws_size,
                              hipStream_t stream) {
    const float* query = (const float*)d_in[0];
    const float* key_  = (const float*)d_in[1];
    const float* value = (const float*)d_in[2];
    const float* mask  = (const float*)d_in[3];
    const float* Wq = (const float*)d_in[4];
    const float* bq = (const float*)d_in[5];
    const float* Wk = (const float*)d_in[6];
    const float* bk = (const float*)d_in[7];
    const float* Wv = (const float*)d_in[8];
    const float* bv = (const float*)d_in[9];
    const float* Wo = (const float*)d_in[10];
    const float* bo = (const float*)d_in[11];

    char* ws = (char*)d_ws;
    u16* wvt  = (u16*)(ws + 0);          // 128 KB
    u16* wot  = (u16*)(ws + 131072);     // 128 KB
    u16* qw   = (u16*)(ws + 262144);     // 512 KB
    u16* kw   = (u16*)(ws + 786432);     // 512 KB
    u16* attn = (u16*)(ws + 1310720);    // 8 MB
    u16* wqt  = (u16*)(ws + 1310720);           // aliases attn (dead before attn written)
    u16* wkt  = (u16*)(ws + 1310720 + 131072);
    u16* ut   = (u16*)(ws + 9699328);    // 64 MiB
    u16* Tm   = (u16*)(ws + 76808192);   // chunk-sized (<= 32 MiB with Nc<=64)
    float* out = (float*)d_out;

    // n-chunking: cap Nc at 64 so the Tm chunk (Nc*512KB <= 32 MiB) stays
    // L3-resident -> pv's Tm writes and wo's Tm reads never round-trip HBM.
    size_t avail = (ws_size > 76808192u) ? (ws_size - 76808192u) : 0;
    int Nc = 64;
    while (Nc > 4 && (size_t)Nc * 524288u > avail) Nc >>= 1;   // T bytes = Nc*512KB
    int nshift = 0;
    while ((1 << nshift) < Nc) nshift++;

    hipLaunchKernelGGL(prep_weights,   dim3(1024), dim3(256), 0, stream, Wq, Wk, Wv, Wo, wqt, wkt, wvt, wot);
    hipLaunchKernelGGL(qk_proj,        dim3(32),   dim3(256), 0, stream, query, key_, wqt, bq, wkt, bk, qw, kw);
    hipLaunchKernelGGL(scores_softmax, dim3(256),  dim3(256), 0, stream, qw, kw, mask, attn);
    hipLaunchKernelGGL(vproj_gemm,     dim3(2048), dim3(256), 0, stream, value, bv, wvt, ut);

    int nTiles = Nc >> 2;                      // 128-wide nc-tiles per (b,h)
    for (int n0 = 0; n0 < NN; n0 += Nc) {
        hipLaunchKernelGGL(pv_gemm, dim3(16 * 4 * nTiles), dim3(256), 0, stream,
                           attn, ut, Tm, n0, nTiles, Nc);
        hipLaunchKernelGGL(wo_gemm, dim3((BB * Nc * LL / 128) * 2), dim3(256), 0, stream,
                           Tm, wot, bo, out, n0, Nc, nshift);
    }
}

// Round 19
// 179.564 us; speedup vs baseline: 1.0427x; 1.0427x over previous
//
#include <hip/hip_runtime.h>
#include <hip/hip_bf16.h>
#include <stdint.h>

// Problem constants
#define BB 2
#define LL 512
#define DIN 256
#define HH 8
#define DKK 32
#define NN 128
#define DM 256            // D_OUT / model dim
#define SCALING 0.17677669529663687f

typedef unsigned short u16;
typedef float f32x4 __attribute__((ext_vector_type(4)));
typedef short s16x8 __attribute__((ext_vector_type(8)));

#define MFMA16(a, b, c) __builtin_amdgcn_mfma_f32_16x16x32_bf16((a), (b), (c), 0, 0, 0)

typedef __attribute__((address_space(3))) char lds_char;
typedef const __attribute__((address_space(1))) char glb_char;

__device__ __forceinline__ void gload16(const void* g, void* l) {
    __builtin_amdgcn_global_load_lds((glb_char*)g, (lds_char*)l, 16, 0, 0);
}

__device__ __forceinline__ u16 f2bf(float f) {
    union { float f; uint32_t i; } v; v.f = f;
    uint32_t x = v.i;
    return (u16)((x + 0x7fffu + ((x >> 16) & 1u)) >> 16);   // RNE
}

// pack 2 floats -> 2 bf16 (round-half-up) in one u32 via v_perm
__device__ __forceinline__ uint32_t pack2bf(float f0, float f1) {
    union { float f; uint32_t i; } a, b;
    a.f = f0; b.f = f1;
    return __builtin_amdgcn_perm(b.i + 0x8000u, a.i + 0x8000u, 0x07060302u);
}

// swizzled LDS frag read, 128B rows (BK=64 bf16): 16B at (row, byte-col cb)
__device__ __forceinline__ s16x8 ldsfrag(const u16* base, int row, int cb) {
    const char* p = (const char*)base + row * 128 + (cb ^ ((row & 7) << 4));
    return *(const s16x8*)(const void*)p;
}

// ---------------------------------------------------------------------------
// Kernel 1: transpose Wq,Wk,Wv,Wo to bf16, K-major (WT[c][k] = W[k][c])
// ---------------------------------------------------------------------------
__global__ __launch_bounds__(256) void prep_weights(
        const float* __restrict__ Wq, const float* __restrict__ Wk,
        const float* __restrict__ Wv, const float* __restrict__ Wo,
        u16* __restrict__ wqt, u16* __restrict__ wkt,
        u16* __restrict__ wvt, u16* __restrict__ wot) {
    int idx = blockIdx.x * 256 + threadIdx.x;      // 0 .. 262143
    int which = idx >> 16;
    const float* src = (which == 0) ? Wq : (which == 1) ? Wk : (which == 2) ? Wv : Wo;
    u16* dst = (which == 0) ? wqt : (which == 1) ? wkt : (which == 2) ? wvt : wot;
    int i = idx & 65535;
    int c = i & 255;
    int k = i >> 8;
    dst[(size_t)c * 256 + k] = f2bf(src[(size_t)k * 256 + c]);
}

// ---------------------------------------------------------------------------
// Kernel 2 (MFMA): q = (query@Wq+bq)*scale, k = key@Wk+bk -> bf16 [b][h][l][32]
// ---------------------------------------------------------------------------
__global__ __launch_bounds__(256) void qk_proj(
        const float* __restrict__ q_in, const float* __restrict__ k_in,
        const u16* __restrict__ wqt, const float* __restrict__ bq,
        const u16* __restrict__ wkt, const float* __restrict__ bk,
        u16* __restrict__ q_ws, u16* __restrict__ k_ws) {
    int bid = blockIdx.x;          // 0..31
    int isK = bid & 1;
    int r0 = (bid >> 1) * 64;
    const float* src = isK ? k_in : q_in;
    const u16* wt    = isK ? wkt : wqt;
    const float* bias = isK ? bk : bq;
    u16* dst = isK ? k_ws : q_ws;
    float scale = isK ? 1.0f : SCALING;

    int t = threadIdx.x, w = t >> 6, l = t & 63, lr = l & 15, lg = l >> 4;

    f32x4 zero = {0.f, 0.f, 0.f, 0.f};
    f32x4 acc[4][4];
#pragma unroll
    for (int m = 0; m < 4; m++)
#pragma unroll
        for (int cf = 0; cf < 4; cf++) acc[m][cf] = zero;

#pragma unroll
    for (int ks = 0; ks < 8; ks++) {
        s16x8 afr[4];
#pragma unroll
        for (int m = 0; m < 4; m++) {
            const float* p = src + (size_t)(r0 + m * 16 + lr) * DIN + ks * 32 + lg * 8;
            float4 v0 = *(const float4*)p;
            float4 v1 = *(const float4*)(p + 4);
            union { u16 u[8]; s16x8 v; } tmp;
            tmp.u[0] = f2bf(v0.x); tmp.u[1] = f2bf(v0.y);
            tmp.u[2] = f2bf(v0.z); tmp.u[3] = f2bf(v0.w);
            tmp.u[4] = f2bf(v1.x); tmp.u[5] = f2bf(v1.y);
            tmp.u[6] = f2bf(v1.z); tmp.u[7] = f2bf(v1.w);
            afr[m] = tmp.v;
        }
        s16x8 bfrg[4];
#pragma unroll
        for (int cf = 0; cf < 4; cf++)
            bfrg[cf] = *(const s16x8*)(const void*)(wt + (size_t)(w * 64 + cf * 16 + lr) * 256 + ks * 32 + lg * 8);
#pragma unroll
        for (int m = 0; m < 4; m++)
#pragma unroll
            for (int cf = 0; cf < 4; cf++) acc[m][cf] = MFMA16(afr[m], bfrg[cf], acc[m][cf]);
    }

#pragma unroll
    for (int m = 0; m < 4; m++)
#pragma unroll
        for (int cf = 0; cf < 4; cf++) {
            int c = w * 64 + cf * 16 + lr;
            int h = c >> 5, dd = c & 31;
            float bv_ = bias[c];
#pragma unroll
            for (int r = 0; r < 4; r++) {
                int row = r0 + m * 16 + 4 * lg + r;
                int b = row >> 9, li = row & 511;
                dst[(((size_t)(b * HH + h)) * LL + li) * DKK + dd] = f2bf((acc[m][cf][r] + bv_) * scale);
            }
        }
}

// ---------------------------------------------------------------------------
// Kernel 3: scores = q@k^T, mask, softmax -> attn bf16 [b][h][i][j]
// ---------------------------------------------------------------------------
__global__ __launch_bounds__(256) void scores_softmax(
        const u16* __restrict__ q_ws, const u16* __restrict__ k_ws,
        const float* __restrict__ mask, u16* __restrict__ attn) {
    int bid = blockIdx.x;
    int it = bid & 15;
    int bh = bid >> 4;
    int b = bh >> 3;
    int i0 = it * 32;

    __shared__ u16 kl[LL][40];
    __shared__ u16 ql[32][40];
    __shared__ float redmx[2][32];
    __shared__ float redsm[2][32];

    int t = threadIdx.x;
    const u16* kbase = k_ws + (size_t)bh * LL * DKK;
#pragma unroll
    for (int x = 0; x < 8; x++) {
        int idx = x * 256 + t;
        int row = idx >> 2, ch = idx & 3;
        *(s16x8*)(void*)(&kl[row][ch * 8]) = *(const s16x8*)(const void*)(kbase + (size_t)row * DKK + ch * 8);
    }
    if (t < 128) {
        const u16* qbase = q_ws + (size_t)bh * LL * DKK + (size_t)i0 * DKK;
        int row = t >> 2, ch = t & 3;
        *(s16x8*)(void*)(&ql[row][ch * 8]) = *(const s16x8*)(const void*)(qbase + (size_t)row * DKK + ch * 8);
    }
    __syncthreads();

    int w = t >> 6, l = t & 63, lr = l & 15, lg = l >> 4;
    int ih = (w & 1) * 16;
    int jh = (w >> 1) * 256;
    int jhalf = w >> 1;

    s16x8 af = *(const s16x8*)(const void*)(&ql[ih + lr][lg * 8]);
    f32x4 zero = {0.f, 0.f, 0.f, 0.f};
    f32x4 acc[16];
#pragma unroll
    for (int cf = 0; cf < 16; cf++) {
        s16x8 bf = *(const s16x8*)(const void*)(&kl[jh + cf * 16 + lr][lg * 8]);
        acc[cf] = MFMA16(af, bf, zero);
    }

    const float* mrow = mask + (size_t)b * LL * LL;
    float attv[16][4];
    float mx[4], sm[4];
#pragma unroll
    for (int r = 0; r < 4; r++) mx[r] = -3.0e38f;
#pragma unroll
    for (int cf = 0; cf < 16; cf++) {
#pragma unroll
        for (int r = 0; r < 4; r++) {
            int irow = i0 + ih + 4 * lg + r;
            int jcol = jh + cf * 16 + lr;
            float mv = mrow[(size_t)irow * LL + jcol];
            float s = (mv < 0.5f) ? -1.0e30f : acc[cf][r];
            attv[cf][r] = s;
            mx[r] = fmaxf(mx[r], s);
        }
    }
#pragma unroll
    for (int d = 1; d < 16; d <<= 1)
#pragma unroll
        for (int r = 0; r < 4; r++) mx[r] = fmaxf(mx[r], __shfl_xor(mx[r], d));
#pragma unroll
    for (int r = 0; r < 4; r++) sm[r] = 0.f;
#pragma unroll
    for (int cf = 0; cf < 16; cf++)
#pragma unroll
        for (int r = 0; r < 4; r++) {
            float p = __expf(attv[cf][r] - mx[r]);
            attv[cf][r] = p;
            sm[r] += p;
        }
#pragma unroll
    for (int d = 1; d < 16; d <<= 1)
#pragma unroll
        for (int r = 0; r < 4; r++) sm[r] += __shfl_xor(sm[r], d);

    if (lr == 0) {
#pragma unroll
        for (int r = 0; r < 4; r++) {
            redmx[jhalf][ih + 4 * lg + r] = mx[r];
            redsm[jhalf][ih + 4 * lg + r] = sm[r];
        }
    }
    __syncthreads();
    float inv[4];
#pragma unroll
    for (int r = 0; r < 4; r++) {
        int row = ih + 4 * lg + r;
        float m0 = redmx[0][row], m1 = redmx[1][row];
        float s0 = redsm[0][row], s1 = redsm[1][row];
        float gm = fmaxf(m0, m1);
        float gs = s0 * __expf(m0 - gm) + s1 * __expf(m1 - gm);
        inv[r] = __expf(mx[r] - gm) / gs;
    }

    u16* abase = attn + (size_t)bh * LL * LL;
#pragma unroll
    for (int cf = 0; cf < 16; cf++)
#pragma unroll
        for (int r = 0; r < 4; r++) {
            int irow = i0 + ih + 4 * lg + r;
            int jcol = jh + cf * 16 + lr;
            abase[(size_t)irow * LL + jcol] = f2bf(attv[cf][r] * inv[r]);
        }
}

// ---------------------------------------------------------------------------
// Kernel 4 (vproj_gemm, counted-vmcnt): C-write -> ut2 layout
// ut2[b][h][n][cl][j] = sum_k wvt[h*32+cl][k]*value[b,n,j][k] + bv
// ---------------------------------------------------------------------------
__global__ __launch_bounds__(256, 2) void vproj_gemm(
        const float* __restrict__ value, const float* __restrict__ bv,
        const u16* __restrict__ wvt, u16* __restrict__ ut) {
    __shared__ __align__(16) u16 sm[2 * 16384];    // per buf: A 16KB + B 16KB

    int t = threadIdx.x;
    int nb = gridDim.x;
    int cpx = nb >> 3;
    int swz = (blockIdx.x & 7) * cpx + (blockIdx.x >> 3);
    int ct = swz & 1;
    int jt = (swz >> 1) & 3;
    int bn = swz >> 3;
    int b = bn >> 7, n_ = bn & 127;
    int c0 = ct * 128, j0 = jt * 128;

    int w = t >> 6, l = t & 63, lr = l & 15, lg = l >> 4;
    int wr = w >> 1, wc = w & 1;

    const float* vbase = value + ((size_t)bn * LL + j0) * DM;

    int srow = t >> 3;         // 0..31 (x adds 32 per step)
    int sgc = t & 7;           // 16B-granule column
    f32x4 zero = {0.f, 0.f, 0.f, 0.f};
    f32x4 acc[4][4];
#pragma unroll
    for (int m = 0; m < 4; m++)
#pragma unroll
        for (int nf = 0; nf < 4; nf++) acc[m][nf] = zero;

    auto stageA = [&](int buf, int kk) {
#pragma unroll
        for (int x = 0; x < 4; x++) {
            int row = x * 32 + srow;
            int gs = sgc ^ (row & 7);
            gload16(wvt + (size_t)(c0 + row) * 256 + kk * 64 + gs * 8,
                    (char*)&sm[buf * 16384] + (x * 256 + t) * 16);
        }
    };
    float4 breg[2][4][2];      // 2 prefetch sets
    auto loadB = [&](int set, int kk) {
#pragma unroll
        for (int x = 0; x < 4; x++) {
            int row = x * 32 + srow;
            const float* p = vbase + (size_t)row * DM + kk * 64 + sgc * 8;
            breg[set][x][0] = *(const float4*)p;
            breg[set][x][1] = *(const float4*)(p + 4);
        }
    };
    auto writeB = [&](int buf, int set) {
#pragma unroll
        for (int x = 0; x < 4; x++) {
            int row = x * 32 + srow;
            uint32_t p0 = pack2bf(breg[set][x][0].x, breg[set][x][0].y);
            uint32_t p1 = pack2bf(breg[set][x][0].z, breg[set][x][0].w);
            uint32_t p2 = pack2bf(breg[set][x][1].x, breg[set][x][1].y);
            uint32_t p3 = pack2bf(breg[set][x][1].z, breg[set][x][1].w);
            uint32_t* dst = (uint32_t*)((char*)&sm[buf * 16384 + 8192]
                            + row * 128 + ((sgc * 16) ^ ((row & 7) << 4)));
            dst[0] = p0; dst[1] = p1; dst[2] = p2; dst[3] = p3;
        }
    };

    stageA(0, 0);
    loadB(0, 0);
    loadB(1, 1);               // prefetch depth 2
    writeB(0, 0);              // reg-wait retires stageA(0)+loadB(0)
    asm volatile("s_waitcnt vmcnt(8) lgkmcnt(0)" ::: "memory");
    __builtin_amdgcn_s_barrier();
    int cur = 0;
#pragma unroll
    for (int kk = 0; kk < 4; kk++) {
        if (kk < 3) stageA(cur ^ 1, kk + 1);
        if (kk < 2) loadB(kk & 1, kk + 2);     // issue 2 steps ahead
        const u16* Ab = &sm[cur * 16384];
        const u16* Bb = &sm[cur * 16384 + 8192];
        s16x8 af[4][2], bf[4][2];
#pragma unroll
        for (int m = 0; m < 4; m++)
#pragma unroll
            for (int ks = 0; ks < 2; ks++)
                af[m][ks] = ldsfrag(Ab, wr * 64 + m * 16 + lr, ks * 64 + lg * 16);
#pragma unroll
        for (int nf = 0; nf < 4; nf++)
#pragma unroll
            for (int ks = 0; ks < 2; ks++)
                bf[nf][ks] = ldsfrag(Bb, wc * 64 + nf * 16 + lr, ks * 64 + lg * 16);
#pragma unroll
        for (int ks = 0; ks < 2; ks++)
#pragma unroll
            for (int m = 0; m < 4; m++)
#pragma unroll
                for (int nf = 0; nf < 4; nf++)
                    acc[m][nf] = MFMA16(af[m][ks], bf[nf][ks], acc[m][nf]);
        if (kk < 3) writeB(cur ^ 1, (kk + 1) & 1);
        // counted-vmcnt barrier: keep loadB prefetch in flight
        if (kk < 2) {
            asm volatile("s_waitcnt vmcnt(8) lgkmcnt(0)" ::: "memory");
            __builtin_amdgcn_s_barrier();
        } else if (kk == 2) {
            asm volatile("s_waitcnt vmcnt(0) lgkmcnt(0)" ::: "memory");
            __builtin_amdgcn_s_barrier();
        }
        cur ^= 1;
    }

    // scalar C-write, ut2 layout: (((b*HH + h)*NN + n)*DKK + cl)*LL + j
#pragma unroll
    for (int m = 0; m < 4; m++) {
#pragma unroll
        for (int rr = 0; rr < 4; rr++) {
            int c = c0 + wr * 64 + m * 16 + 4 * lg + rr;
            int h = c >> 5, cl = c & 31;
            float bvv = bv[c];
            u16* dst = ut + ((((size_t)(b * HH + h)) * NN + n_) * DKK + cl) * LL + j0;
#pragma unroll
            for (int nf = 0; nf < 4; nf++) {
                int j_l = wc * 64 + nf * 16 + lr;
                dst[j_l] = f2bf(acc[m][nf][rr] + bvv);
            }
        }
    }
}

// ---------------------------------------------------------------------------
// Kernel 5 (pv, 2-buf BK=64, contiguous B panel):
// T[i][nc] = sum_j attn[b,h,i,j] * ut2[b,h, n(nc), cl(nc)][j]
// ---------------------------------------------------------------------------
__global__ __launch_bounds__(256, 2) void pv_gemm(
        const u16* __restrict__ attn, const u16* __restrict__ ut,
        u16* __restrict__ Tm, int n0, int nTiles, int Nc) {
    __shared__ __align__(16) u16 sm[2 * 16384];    // 2 bufs x (A 8192 + B 8192) u16 = 64KB

    int t = threadIdx.x;
    int nb = gridDim.x;
    int cpx = nb >> 3;
    int swz = (blockIdx.x & 7) * cpx + (blockIdx.x >> 3);
    int nct = swz % nTiles;
    int tmp2 = swz / nTiles;
    int it = tmp2 & 3;
    int bh = tmp2 >> 2;
    int b = bh >> 3, h = bh & 7;
    int i0 = it * 128;

    int w = t >> 6, l = t & 63, lr = l & 15, lg = l >> 4;
    int wr = w >> 1, wc = w & 1;

    const u16* arow0 = attn + (size_t)bh * LL * LL + (size_t)i0 * LL;
    // contiguous B panel: rows (nct*128 + row) of ut2[b][h][n][cl][j]
    const u16* uB = ut + (((size_t)(b * HH + h)) * NN + n0) * DKK * LL;

    f32x4 zero = {0.f, 0.f, 0.f, 0.f};
    f32x4 acc[4][4];
#pragma unroll
    for (int m = 0; m < 4; m++)
#pragma unroll
        for (int nf = 0; nf < 4; nf++) acc[m][nf] = zero;

    auto stage = [&](int buf, int kk) {
#pragma unroll
        for (int x = 0; x < 4; x++) {              // A tile: 128 rows x 128B
            int G = x * 256 + t;
            int row = G >> 3, gc = G & 7;
            int gs = gc ^ (row & 7);
            gload16(arow0 + (size_t)row * LL + kk * 64 + gs * 8,
                    (char*)&sm[buf * 16384] + G * 16);
        }
#pragma unroll
        for (int x = 0; x < 4; x++) {              // B tile: 128 contiguous rows x 128B
            int G = x * 256 + t;
            int row = G >> 3, gc = G & 7;
            int gs = gc ^ (row & 7);
            gload16(uB + (size_t)(nct * 128 + row) * LL + kk * 64 + gs * 8,
                    (char*)&sm[buf * 16384 + 8192] + G * 16);
        }
    };

    stage(0, 0);
    __syncthreads();
    int cur = 0;
    for (int kk = 0; kk < 8; kk++) {
        if (kk < 7) stage(cur ^ 1, kk + 1);
        const u16* Ab = &sm[cur * 16384];
        const u16* Bb = &sm[cur * 16384 + 8192];
        s16x8 af[4][2], bf[4][2];
#pragma unroll
        for (int m = 0; m < 4; m++)
#pragma unroll
            for (int ks = 0; ks < 2; ks++)
                af[m][ks] = ldsfrag(Ab, wr * 64 + m * 16 + lr, ks * 64 + lg * 16);
#pragma unroll
        for (int nf = 0; nf < 4; nf++)
#pragma unroll
            for (int ks = 0; ks < 2; ks++)
                bf[nf][ks] = ldsfrag(Bb, wc * 64 + nf * 16 + lr, ks * 64 + lg * 16);
#pragma unroll
        for (int ks = 0; ks < 2; ks++)
#pragma unroll
            for (int m = 0; m < 4; m++)
#pragma unroll
                for (int nf = 0; nf < 4; nf++)
                    acc[m][nf] = MFMA16(af[m][ks], bf[nf][ks], acc[m][nf]);
        __syncthreads();
        cur ^= 1;
    }

    // scalar C-write, Tm layout unchanged
#pragma unroll
    for (int m = 0; m < 4; m++) {
        int i = i0 + wr * 64 + m * 16 + 4 * lg;
#pragma unroll
        for (int nf = 0; nf < 4; nf++) {
            int nc = nct * 128 + wc * 64 + nf * 16 + lr;
            int nl = nc >> 5, cl = nc & 31;
            u16* dst = Tm + (((size_t)(b * Nc + nl)) * LL + i) * DM + h * DKK + cl;
#pragma unroll
            for (int rr = 0; rr < 4; rr++)
                dst[(size_t)rr * DM] = f2bf(acc[m][nf][rr]);
        }
    }
}

// ---------------------------------------------------------------------------
// Kernel 6 (wo): out[r][o] = sum_cc T[r][cc] * wot[o][cc] + bo[o]
// ---------------------------------------------------------------------------
__global__ __launch_bounds__(256, 2) void wo_gemm(
        const u16* __restrict__ Tm, const u16* __restrict__ wot,
        const float* __restrict__ bo, float* __restrict__ out,
        int n0, int Nc, int nshift) {
    __shared__ __align__(16) u16 sm[2 * 16384];

    int t = threadIdx.x;
    int nb = gridDim.x;
    int cpx = nb >> 3;
    int swz = (blockIdx.x & 7) * cpx + (blockIdx.x >> 3);
    int oc = swz & 1;
    int mt = swz >> 1;
    int r0 = mt * 128;

    int w = t >> 6, l = t & 63, lr = l & 15, lg = l >> 4;
    int wr = w >> 1, wc = w & 1;

    f32x4 zero = {0.f, 0.f, 0.f, 0.f};
    f32x4 acc[4][4];
#pragma unroll
    for (int m = 0; m < 4; m++)
#pragma unroll
        for (int nf = 0; nf < 4; nf++) acc[m][nf] = zero;

    auto stage = [&](int buf, int kk) {
#pragma unroll
        for (int x = 0; x < 4; x++) {              // A: T rows
            int G = x * 256 + t;
            int row = G >> 3, gc = G & 7;
            int gs = gc ^ (row & 7);
            gload16(Tm + (size_t)(r0 + row) * DM + kk * 64 + gs * 8,
                    (char*)&sm[buf * 16384] + G * 16);
        }
#pragma unroll
        for (int x = 0; x < 4; x++) {              // B: wot rows
            int G = x * 256 + t;
            int row = G >> 3, gc = G & 7;
            int gs = gc ^ (row & 7);
            gload16(wot + (size_t)(oc * 128 + row) * DM + kk * 64 + gs * 8,
                    (char*)&sm[buf * 16384 + 8192] + G * 16);
        }
    };

    stage(0, 0);
    __syncthreads();
    int cur = 0;
    for (int kk = 0; kk < 4; kk++) {
        if (kk < 3) stage(cur ^ 1, kk + 1);
        const u16* Ab = &sm[cur * 16384];
        const u16* Bb = &sm[cur * 16384 + 8192];
        s16x8 af[4][2], bf[4][2];
#pragma unroll
        for (int m = 0; m < 4; m++)
#pragma unroll
            for (int ks = 0; ks < 2; ks++)
                af[m][ks] = ldsfrag(Ab, wr * 64 + m * 16 + lr, ks * 64 + lg * 16);
#pragma unroll
        for (int nf = 0; nf < 4; nf++)
#pragma unroll
            for (int ks = 0; ks < 2; ks++)
                bf[nf][ks] = ldsfrag(Bb, wc * 64 + nf * 16 + lr, ks * 64 + lg * 16);
#pragma unroll
        for (int ks = 0; ks < 2; ks++)
#pragma unroll
            for (int m = 0; m < 4; m++)
#pragma unroll
                for (int nf = 0; nf < 4; nf++)
                    acc[m][nf] = MFMA16(af[m][ks], bf[nf][ks], acc[m][nf]);
        __syncthreads();
        cur ^= 1;
    }

#pragma unroll
    for (int nf = 0; nf < 4; nf++) {
        int ocol = oc * 128 + wc * 64 + nf * 16 + lr;
        float bov = bo[ocol];
#pragma unroll
        for (int m = 0; m < 4; m++) {
            int rbase = r0 + wr * 64 + m * 16 + 4 * lg;
#pragma unroll
            for (int rr = 0; rr < 4; rr++) {
                int r = rbase + rr;
                int bnl = r >> 9, i = r & 511;
                int b = bnl >> nshift, nl = bnl & (Nc - 1);
                out[(((size_t)(b * NN + n0 + nl)) * LL + i) * DM + ocol] = acc[m][nf][rr] + bov;
            }
        }
    }
}

// ---------------------------------------------------------------------------
extern "C" void kernel_launch(void* const* d_in, const int* in_sizes, int n_in,
                              void* d_out, int out_size, void* d_ws, size_t ws_size,
                              hipStream_t stream) {
    const float* query = (const float*)d_in[0];
    const float* key_  = (const float*)d_in[1];
    const float* value = (const float*)d_in[2];
    const float* mask  = (const float*)d_in[3];
    const float* Wq = (const float*)d_in[4];
    const float* bq = (const float*)d_in[5];
    const float* Wk = (const float*)d_in[6];
    const float* bk = (const float*)d_in[7];
    const float* Wv = (const float*)d_in[8];
    const float* bv = (const float*)d_in[9];
    const float* Wo = (const float*)d_in[10];
    const float* bo = (const float*)d_in[11];

    char* ws = (char*)d_ws;
    u16* wvt  = (u16*)(ws + 0);          // 128 KB
    u16* wot  = (u16*)(ws + 131072);     // 128 KB
    u16* qw   = (u16*)(ws + 262144);     // 512 KB
    u16* kw   = (u16*)(ws + 786432);     // 512 KB
    u16* attn = (u16*)(ws + 1310720);    // 8 MB
    u16* wqt  = (u16*)(ws + 1310720);           // aliases attn (dead before attn written)
    u16* wkt  = (u16*)(ws + 1310720 + 131072);
    u16* ut   = (u16*)(ws + 9699328);    // 64 MiB
    u16* Tm   = (u16*)(ws + 76808192);   // chunk-sized (<= 32 MiB with Nc<=64)
    float* out = (float*)d_out;

    // n-chunking: cap Nc at 64 so the Tm chunk (Nc*512KB <= 32 MiB) stays
    // L3-resident -> pv's Tm writes and wo's Tm reads never round-trip HBM.
    size_t avail = (ws_size > 76808192u) ? (ws_size - 76808192u) : 0;
    int Nc = 64;
    while (Nc > 4 && (size_t)Nc * 524288u > avail) Nc >>= 1;   // T bytes = Nc*512KB
    int nshift = 0;
    while ((1 << nshift) < Nc) nshift++;

    hipLaunchKernelGGL(prep_weights,   dim3(1024), dim3(256), 0, stream, Wq, Wk, Wv, Wo, wqt, wkt, wvt, wot);
    hipLaunchKernelGGL(qk_proj,        dim3(32),   dim3(256), 0, stream, query, key_, wqt, bq, wkt, bk, qw, kw);
    hipLaunchKernelGGL(scores_softmax, dim3(256),  dim3(256), 0, stream, qw, kw, mask, attn);
    hipLaunchKernelGGL(vproj_gemm,     dim3(2048), dim3(256), 0, stream, value, bv, wvt, ut);

    int nTiles = Nc >> 2;                      // 128-wide nc-tiles per (b,h)
    for (int n0 = 0; n0 < NN; n0 += Nc) {
        hipLaunchKernelGGL(pv_gemm, dim3(16 * 4 * nTiles), dim3(256), 0, stream,
                           attn, ut, Tm, n0, nTiles, Nc);
        hipLaunchKernelGGL(wo_gemm, dim3((BB * Nc * LL / 128) * 2), dim3(256), 0, stream,
                           Tm, wot, bo, out, n0, Nc, nshift);
    }
}